// Round 8
// baseline (53.670 us; speedup 1.0000x reference)
//
#include <hip/hip_runtime.h>
#include <stdint.h>

#define NS 9

typedef _Float16 f16x8 __attribute__((ext_vector_type(8)));
typedef float    f32x4 __attribute__((ext_vector_type(4)));

#define SBAR __builtin_amdgcn_sched_barrier(0)
#define WAIT_VM(N) do { SBAR; asm volatile("s_waitcnt vmcnt(" #N ")" ::: "memory"); SBAR; } while (0)

__device__ __forceinline__ unsigned int pk(float a, float b) {
    return __builtin_bit_cast(unsigned int, __builtin_amdgcn_cvt_pkrtz(a, b));
}

// out[b,h,A,C,j] = sum_d q[b,h,A,C,d]*relw[63+j-C,d] + q[b,h,C,A,d]*relh[63+j-C,d]
// v8: ZERO LDS / ZERO barriers. v7 showed the MFMA pipe is nearly free; the
// remaining floor was q's LDS round-trip (global->reg->cvt->ds_write->lgkm->
// ds_read) + low occupancy. The 16x16x32 A-layout (row=lane&15, d=ks*32+
// (lane>>4)*8+i) is directly loadable per-lane from q for BOTH terms, and the
// B-layout (col j=lane&15 -> rel row 63-c+j, same d mapping) directly from the
// rel tables (row clamped to 71; cols j>=9 are garbage but never stored).
// Per wave (uniform c): 8 rel loads + 32 q float4 loads, 16-deep counted-vmcnt
// pipeline, 4 f16x8 cvts + 4 MFMA per quadrant, 16 MFMA total, f32 accum.
// Layouts verified on HW by v7 (passed, absmax 0.031).

__global__ __launch_bounds__(256, 4) void relpos_kernel(
    const float* __restrict__ q,
    const float* __restrict__ relh,
    const float* __restrict__ relw,
    float* __restrict__ out)
{
    const int bh   = blockIdx.x & 127;  // b*8 + h
    const int g    = blockIdx.x >> 7;   // c-group 0..15
    const int lane = threadIdx.x & 63;
    const int wvu  = __builtin_amdgcn_readfirstlane(threadIdx.x >> 6);
    const int c    = __builtin_amdgcn_readfirstlane((g << 2) + wvu);  // uniform

    const int jl   = lane & 15;         // A-row / B-col within 16
    const int koff = (lane >> 4) << 3;  // d-chunk offset within 32-d half

    const float* __restrict__ qs = q + ((size_t)bh << 18);

    // ---- B loads: rel row 63-c+jl (clamped), both tables, both d-halves ----
    int rl = 63 - c + jl; rl = (rl > 71) ? 71 : rl;
    const float* hp = relh + (size_t)rl * 64 + koff;
    const float* wp = relw + (size_t)rl * 64 + koff;
    float4 bh00 = *(const float4*)(hp);          // [vm 1]
    float4 bh01 = *(const float4*)(hp + 4);      // 2
    float4 bh10 = *(const float4*)(hp + 32);     // 3
    float4 bh11 = *(const float4*)(hp + 36);     // 4
    float4 bw00 = *(const float4*)(wp);          // 5
    float4 bw01 = *(const float4*)(wp + 4);      // 6
    float4 bw10 = *(const float4*)(wp + 32);     // 7
    float4 bw11 = *(const float4*)(wp + 36);     // 8
    SBAR;

    // term0: A[a][d] = q[bh, c, a, d]   term1: A[a][d] = q[bh, a, c, d]
    auto ldT0 = [&](int m, float4 v[4]) {
        const float* p = qs + (size_t)c * 4096 + (size_t)((m << 4) + jl) * 64 + koff;
        v[0] = *(const float4*)(p);      v[1] = *(const float4*)(p + 4);
        v[2] = *(const float4*)(p + 32); v[3] = *(const float4*)(p + 36);
    };
    auto ldT1 = [&](int m, float4 v[4]) {
        const float* p = qs + (size_t)((m << 4) + jl) * 4096 + (size_t)c * 64 + koff;
        v[0] = *(const float4*)(p);      v[1] = *(const float4*)(p + 4);
        v[2] = *(const float4*)(p + 32); v[3] = *(const float4*)(p + 36);
    };
    auto mk = [&](const float4& a, const float4& b) -> f16x8 {
        uint4 u;
        u.x = pk(a.x, a.y); u.y = pk(a.z, a.w);
        u.z = pk(b.x, b.y); u.w = pk(b.z, b.w);
        return __builtin_bit_cast(f16x8, u);
    };

    float4 s0[4], s1[4], s2[4], s3[4];
    f32x4 acc0 = {0.f,0.f,0.f,0.f}, acc1 = acc0, acc2 = acc0, acc3 = acc0;

    ldT0(0, s0); ldT0(1, s1); SBAR;     // [vm 16]
    WAIT_VM(8);                          // B arrived
    const f16x8 b00 = mk(bh00, bh01), b01 = mk(bh10, bh11);
    const f16x8 b10 = mk(bw00, bw01), b11 = mk(bw10, bw11);
    ldT0(2, s2); ldT0(3, s3); SBAR;     // [vm 16]
    WAIT_VM(8);                          // s0,s1 (T0 m0,m1) arrived
    acc0 = __builtin_amdgcn_mfma_f32_16x16x32_f16(mk(s0[0], s0[1]), b00, acc0, 0, 0, 0);
    acc0 = __builtin_amdgcn_mfma_f32_16x16x32_f16(mk(s0[2], s0[3]), b01, acc0, 0, 0, 0);
    acc1 = __builtin_amdgcn_mfma_f32_16x16x32_f16(mk(s1[0], s1[1]), b00, acc1, 0, 0, 0);
    acc1 = __builtin_amdgcn_mfma_f32_16x16x32_f16(mk(s1[2], s1[3]), b01, acc1, 0, 0, 0);
    ldT1(0, s0); ldT1(1, s1); SBAR;     // [vm 16]
    WAIT_VM(8);                          // s2,s3 (T0 m2,m3) arrived
    acc2 = __builtin_amdgcn_mfma_f32_16x16x32_f16(mk(s2[0], s2[1]), b00, acc2, 0, 0, 0);
    acc2 = __builtin_amdgcn_mfma_f32_16x16x32_f16(mk(s2[2], s2[3]), b01, acc2, 0, 0, 0);
    acc3 = __builtin_amdgcn_mfma_f32_16x16x32_f16(mk(s3[0], s3[1]), b00, acc3, 0, 0, 0);
    acc3 = __builtin_amdgcn_mfma_f32_16x16x32_f16(mk(s3[2], s3[3]), b01, acc3, 0, 0, 0);
    ldT1(2, s2); ldT1(3, s3); SBAR;     // [vm 16]
    WAIT_VM(8);                          // s0,s1 (T1 m0,m1) arrived
    acc0 = __builtin_amdgcn_mfma_f32_16x16x32_f16(mk(s0[0], s0[1]), b10, acc0, 0, 0, 0);
    acc0 = __builtin_amdgcn_mfma_f32_16x16x32_f16(mk(s0[2], s0[3]), b11, acc0, 0, 0, 0);
    acc1 = __builtin_amdgcn_mfma_f32_16x16x32_f16(mk(s1[0], s1[1]), b10, acc1, 0, 0, 0);
    acc1 = __builtin_amdgcn_mfma_f32_16x16x32_f16(mk(s1[2], s1[3]), b11, acc1, 0, 0, 0);
    WAIT_VM(0);                          // s2,s3 (T1 m2,m3) arrived
    acc2 = __builtin_amdgcn_mfma_f32_16x16x32_f16(mk(s2[0], s2[1]), b10, acc2, 0, 0, 0);
    acc2 = __builtin_amdgcn_mfma_f32_16x16x32_f16(mk(s2[2], s2[3]), b11, acc2, 0, 0, 0);
    acc3 = __builtin_amdgcn_mfma_f32_16x16x32_f16(mk(s3[0], s3[1]), b10, acc3, 0, 0, 0);
    acc3 = __builtin_amdgcn_mfma_f32_16x16x32_f16(mk(s3[2], s3[3]), b11, acc3, 0, 0, 0);

    // ---- store: lane holds cols j=lane&15 (<9), rows a=(lane>>4)*4+reg ----
    if (jl < NS) {
        const int ar = (lane >> 4) << 2;
        const size_t ob = (size_t)bh << 6;
#pragma unroll
        for (int r = 0; r < 4; ++r) {
            out[((ob + ( 0 + ar + r)) * 64 + c) * NS + jl] = acc0[r];
            out[((ob + (16 + ar + r)) * 64 + c) * NS + jl] = acc1[r];
            out[((ob + (32 + ar + r)) * 64 + c) * NS + jl] = acc2[r];
            out[((ob + (48 + ar + r)) * 64 + c) * NS + jl] = acc3[r];
        }
    }
}

extern "C" void kernel_launch(void* const* d_in, const int* in_sizes, int n_in,
                              void* d_out, int out_size, void* d_ws, size_t ws_size,
                              hipStream_t stream) {
    const float* q    = (const float*)d_in[0];
    const float* relh = (const float*)d_in[3];
    const float* relw = (const float*)d_in[4];
    float* out = (float*)d_out;

    // grid: 16 c-groups x 128 (b,h); same-bh blocks are 128 apart -> same XCD
    relpos_kernel<<<dim3(2048), dim3(256), 0, stream>>>(q, relh, relw, out);
}